// Round 7
// baseline (905.295 us; speedup 1.0000x reference)
//
#include <hip/hip_runtime.h>
#include <hip/hip_bf16.h>

// E=128 GH=8 GD=16 GL=3 | SH=4 SD=32 SL=4 | N=32 GC=64 GS=16 DEG=64 BMOL=16
// M_conf=4096 M_scaf=1024 M_tot=5120. All float tensors fp32.

// ---------------------------------------------------------------- LN helper (block of 128 threads)
__device__ __forceinline__ float blk_norm(float v, int e, float* sred)
{
  float s = v;
  #pragma unroll
  for (int o = 1; o < 64; o <<= 1) s += __shfl_xor(s, o);
  if ((e & 63) == 0) sred[e >> 6] = s;
  __syncthreads();
  float mean = (sred[0] + sred[1]) * (1.0f / 128.0f);
  __syncthreads();
  float d = v - mean;
  float s2 = d * d;
  #pragma unroll
  for (int o = 1; o < 64; o <<= 1) s2 += __shfl_xor(s2, o);
  if ((e & 63) == 0) sred[e >> 6] = s2;
  __syncthreads();
  float var = (sred[0] + sred[1]) * (1.0f / 128.0f);
  __syncthreads();
  return d / sqrtf(var + 1e-5f);
}

// ---------------------------------------------------------------- node projection (+ zero aggr)
__global__ __launch_bounds__(128) void node_proj_k(
    const float* __restrict__ cx, const float* __restrict__ sx,
    const float* __restrict__ w, const float* __restrict__ b,
    float* __restrict__ h, float* __restrict__ aggr)
{
  int r = blockIdx.x, e = threadIdx.x;
  const float* x = (r < 2048) ? (cx + (size_t)r * 64) : (sx + (size_t)(r - 2048) * 64);
  __shared__ float xs[64];
  if (e < 64) xs[e] = x[e];
  __syncthreads();
  float acc = b[e];
  for (int a = 0; a < 64; a++) acc += xs[a] * w[a * 128 + e];
  h[(size_t)r * 128 + e] = acc;
  aggr[(size_t)r * 128 + e] = 0.0f;
}

// ---------------------------------------------------------------- pairwise distance per graph
__global__ __launch_bounds__(256) void dist_k(
    const float* __restrict__ cpos, const float* __restrict__ spos, float* __restrict__ dist)
{
  int g = blockIdx.x, tid = threadIdx.x;
  __shared__ float P[96];
  const float* p = (g < 64) ? (cpos + (size_t)g * 96) : (spos + (size_t)(g - 64) * 96);
  if (tid < 96) P[tid] = p[tid];
  __syncthreads();
  #pragma unroll
  for (int jj = 0; jj < 4; jj++) {
    int idx = tid * 4 + jj;
    int i = idx >> 5, j = idx & 31;
    float dx = P[i * 3 + 0] - P[j * 3 + 0];
    float dy = P[i * 3 + 1] - P[j * 3 + 1];
    float dz = P[i * 3 + 2] - P[j * 3 + 2];
    float d2 = dx * dx + dy * dy + dz * dz;
    dist[(size_t)g * 1024 + idx] = (d2 > 0.0f) ? sqrtf(d2) : 0.0f;
  }
}

// ---------------------------------------------------------------- EdgeNetwork GEMM + atomic scatter
// 64-edge tile x 14-kt chunk; micro 4 rows(spread) x 8 cols(broadcast). grid (80, 14).
__global__ __launch_bounds__(256) void edge_gemm_k(
    const float* __restrict__ cea, const float* __restrict__ sea,
    const int* __restrict__ cei, const int* __restrict__ sei,
    const float* __restrict__ h,
    const float* __restrict__ elw, const float* __restrict__ elb,
    float* __restrict__ aggr)
{
  __shared__ float efs[64][4];
  __shared__ float hds[64][128];
  __shared__ float As[32][68];     // 272B rows, 16B-aligned
  __shared__ float Bs[32][136];
  __shared__ int srcs[64], dsts[64];
  const int tid = threadIdx.x;
  const int m0 = blockIdx.x * 64;
  const int kt0 = blockIdx.y * 14;
  const int c0 = kt0 >> 2;         // 14 kts span at most 4 c's (14 = 2 mod 4 alignment)
  if (tid < 64) {
    int m = m0 + tid;
    int src, dst;
    if (m < 4096) { src = cei[m]; dst = cei[4096 + m]; }
    else { src = sei[m - 4096] + 2048; dst = sei[1024 + (m - 4096)] + 2048; }
    srcs[tid] = src; dsts[tid] = dst;
  }
  __syncthreads();
  for (int i = tid; i < 2048; i += 256) {
    int t = i >> 5, f = (i & 31) * 4;
    *(float4*)&hds[t][f] = *(const float4*)(h + (size_t)dsts[t] * 128 + f);
  }
  {
    int t = tid >> 2, cc = tid & 3;
    int c = c0 + cc;
    int m = m0 + t;
    const float* attr = (m < 4096) ? (cea + (size_t)m * 17) : (sea + (size_t)(m - 4096) * 17);
    float val;
    if (c < 16) val = attr[c];
    else if (c < 48) {
      float d = fminf(fmaxf(attr[16], 0.0f), 10.0f);
      float t2 = d - (float)((c - 16) * (5.0 / 31.0));
      val = expf(-38.44f * t2 * t2);
    } else val = 1.0f;
    efs[t][cc] = val;
  }
  const int rg = tid & 15, cg = tid >> 4;
  const int r0 = rg * 4, e0 = cg * 8;
  const int gk = tid & 31, ge = (tid >> 5) * 8;
  const int se = tid >> 1, sk = (tid & 1) * 16;
  float acc[4][8] = {};
  __syncthreads();
  #pragma unroll 1
  for (int kt = kt0; kt < kt0 + 14; kt++) {
    int c = kt >> 2, cc = c - c0, f0 = (kt & 3) * 32;
    float4 a0, a1;
    a0.x = efs[ge + 0][cc] * hds[ge + 0][f0 + gk];
    a0.y = efs[ge + 1][cc] * hds[ge + 1][f0 + gk];
    a0.z = efs[ge + 2][cc] * hds[ge + 2][f0 + gk];
    a0.w = efs[ge + 3][cc] * hds[ge + 3][f0 + gk];
    a1.x = efs[ge + 4][cc] * hds[ge + 4][f0 + gk];
    a1.y = efs[ge + 5][cc] * hds[ge + 5][f0 + gk];
    a1.z = efs[ge + 6][cc] * hds[ge + 6][f0 + gk];
    a1.w = efs[ge + 7][cc] * hds[ge + 7][f0 + gk];
    *(float4*)&As[gk][ge] = a0;
    *(float4*)&As[gk][ge + 4] = a1;
    const float* bp = ((c < 48) ? (elw + (size_t)c * 16384) : elb) + (size_t)se * 128 + f0 + sk;
    float4 w0 = *(const float4*)(bp + 0);
    float4 w1 = *(const float4*)(bp + 4);
    float4 w2 = *(const float4*)(bp + 8);
    float4 w3 = *(const float4*)(bp + 12);
    Bs[sk + 0][se] = w0.x;  Bs[sk + 1][se] = w0.y;  Bs[sk + 2][se] = w0.z;  Bs[sk + 3][se] = w0.w;
    Bs[sk + 4][se] = w1.x;  Bs[sk + 5][se] = w1.y;  Bs[sk + 6][se] = w1.z;  Bs[sk + 7][se] = w1.w;
    Bs[sk + 8][se] = w2.x;  Bs[sk + 9][se] = w2.y;  Bs[sk + 10][se] = w2.z; Bs[sk + 11][se] = w2.w;
    Bs[sk + 12][se] = w3.x; Bs[sk + 13][se] = w3.y; Bs[sk + 14][se] = w3.z; Bs[sk + 15][se] = w3.w;
    __syncthreads();
    #pragma unroll
    for (int kk = 0; kk < 32; kk++) {
      float4 a = *(const float4*)&As[kk][r0];
      float4 b0 = *(const float4*)&Bs[kk][e0];
      float4 b1 = *(const float4*)&Bs[kk][e0 + 4];
      acc[0][0] += a.x * b0.x; acc[0][1] += a.x * b0.y; acc[0][2] += a.x * b0.z; acc[0][3] += a.x * b0.w;
      acc[0][4] += a.x * b1.x; acc[0][5] += a.x * b1.y; acc[0][6] += a.x * b1.z; acc[0][7] += a.x * b1.w;
      acc[1][0] += a.y * b0.x; acc[1][1] += a.y * b0.y; acc[1][2] += a.y * b0.z; acc[1][3] += a.y * b0.w;
      acc[1][4] += a.y * b1.x; acc[1][5] += a.y * b1.y; acc[1][6] += a.y * b1.z; acc[1][7] += a.y * b1.w;
      acc[2][0] += a.z * b0.x; acc[2][1] += a.z * b0.y; acc[2][2] += a.z * b0.z; acc[2][3] += a.z * b0.w;
      acc[2][4] += a.z * b1.x; acc[2][5] += a.z * b1.y; acc[2][6] += a.z * b1.z; acc[2][7] += a.z * b1.w;
      acc[3][0] += a.w * b0.x; acc[3][1] += a.w * b0.y; acc[3][2] += a.w * b0.z; acc[3][3] += a.w * b0.w;
      acc[3][4] += a.w * b1.x; acc[3][5] += a.w * b1.y; acc[3][6] += a.w * b1.z; acc[3][7] += a.w * b1.w;
    }
    __syncthreads();
  }
  #pragma unroll
  for (int i = 0; i < 4; i++) {
    float* dst = aggr + (size_t)srcs[r0 + i] * 128 + e0;
    #pragma unroll
    for (int j = 0; j < 8; j++) atomicAdd(dst + j, acc[i][j]);
  }
}

// ---------------------------------------------------------------- BM=16 GEMM body: Cp = A@Bp + biasp (K=128)
__device__ __forceinline__ void gemm16_body(
    const float* __restrict__ A, const float* __restrict__ Bp,
    const float* __restrict__ biasp, float* __restrict__ Cp,
    int row0, int ldb, int ldc)
{
  __shared__ float Sa[32][20];
  __shared__ float Bs[32][136];
  const int tid = threadIdx.x;
  const int tm = tid >> 5, tn = tid & 31;
  const int t0 = 2 * tm, e0 = 4 * tn;
  const int ar = tid >> 4, ak = (tid & 15) * 2;
  const int bk = tid >> 3, be = (tid & 7) * 16;
  float acc[2][4] = {};
  for (int k0 = 0; k0 < 128; k0 += 32) {
    float2 av = *(const float2*)(A + (size_t)(row0 + ar) * 128 + k0 + ak);
    Sa[ak][ar] = av.x; Sa[ak + 1][ar] = av.y;
    const float* bp = Bp + (size_t)(k0 + bk) * ldb + be;
    float4 b0v = *(const float4*)(bp + 0);
    float4 b1v = *(const float4*)(bp + 4);
    float4 b2v = *(const float4*)(bp + 8);
    float4 b3v = *(const float4*)(bp + 12);
    Bs[bk][be + 0] = b0v.x;  Bs[bk][be + 1] = b0v.y;  Bs[bk][be + 2] = b0v.z;  Bs[bk][be + 3] = b0v.w;
    Bs[bk][be + 4] = b1v.x;  Bs[bk][be + 5] = b1v.y;  Bs[bk][be + 6] = b1v.z;  Bs[bk][be + 7] = b1v.w;
    Bs[bk][be + 8] = b2v.x;  Bs[bk][be + 9] = b2v.y;  Bs[bk][be + 10] = b2v.z; Bs[bk][be + 11] = b2v.w;
    Bs[bk][be + 12] = b3v.x; Bs[bk][be + 13] = b3v.y; Bs[bk][be + 14] = b3v.z; Bs[bk][be + 15] = b3v.w;
    __syncthreads();
    #pragma unroll
    for (int kk = 0; kk < 32; kk++) {
      float2 a = *(const float2*)&Sa[kk][t0];
      float4 b = *(const float4*)&Bs[kk][e0];
      acc[0][0] += a.x * b.x; acc[0][1] += a.x * b.y; acc[0][2] += a.x * b.z; acc[0][3] += a.x * b.w;
      acc[1][0] += a.y * b.x; acc[1][1] += a.y * b.y; acc[1][2] += a.y * b.z; acc[1][3] += a.y * b.w;
    }
    __syncthreads();
  }
  #pragma unroll
  for (int i = 0; i < 2; i++) {
    float* cp = Cp + (size_t)(row0 + t0 + i) * ldc + e0;
    #pragma unroll
    for (int j = 0; j < 4; j++) cp[j] = acc[i][j] + biasp[e0 + j];
  }
}

// ---------------------------------------------------------------- merged QKV: graph (3x160) + seq (3x128)
__global__ __launch_bounds__(256) void qkv_k(
    int gBlocks,
    const float* __restrict__ ghb,
    const float* gqw, const float* gkw, const float* gvw,
    const float* gqb, const float* gkb, const float* gvb, float* gout,
    const float* __restrict__ sxs, const float* sw, const float* sb, float* sout)
{
  int bx = blockIdx.x;
  if (bx < gBlocks) {
    int z = bx / 160, rt = bx % 160;
    const float* B = (z == 0) ? gqw : (z == 1) ? gkw : gvw;
    const float* bias = (z == 0) ? gqb : (z == 1) ? gkb : gvb;
    gemm16_body(ghb, B, bias, gout + (size_t)z * 327680, rt * 16, 128, 128);
  } else {
    int i = bx - gBlocks;
    int z = i >> 7, rt = i & 127;
    gemm16_body(sxs, sw + z * 128, sb + z * 128, sout + z * 128, rt * 16, 384, 384);
  }
}

// ---------------------------------------------------------------- graph attention body (N=32, GD=16)
__device__ __forceinline__ void gattn_body(
    int g, int h, const float* __restrict__ q, const float* __restrict__ k,
    const float* __restrict__ v, const float* __restrict__ dist, float* __restrict__ o)
{
  __shared__ float qs[32][17], ksh[32][17], vsh[32][17], ss[32][33], rs[32];
  const int tid = threadIdx.x;
  {
    int idx = tid * 2;
    int i = idx >> 4, d = idx & 15;
    size_t base = ((size_t)(g * 32 + i)) * 128 + h * 16 + d;
    qs[i][d] = q[base];  qs[i][d + 1] = q[base + 1];
    ksh[i][d] = k[base]; ksh[i][d + 1] = k[base + 1];
    vsh[i][d] = v[base]; vsh[i][d + 1] = v[base + 1];
  }
  __syncthreads();
  {
    int i = tid >> 3, j0 = (tid & 7) * 4;
    for (int j = j0; j < j0 + 4; j++) {
      float a = 0;
      #pragma unroll
      for (int d = 0; d < 16; d++) a += qs[i][d] * ksh[j][d];
      a = a * 0.25f + dist[(size_t)g * 1024 + i * 32 + j];
      ss[i][j] = fminf(fmaxf(a, -10.0f), 10.0f);
    }
  }
  __syncthreads();
  if (tid < 32) {
    float m = -1e30f;
    for (int j = 0; j < 32; j++) m = fmaxf(m, ss[tid][j]);
    float sm = 0;
    for (int j = 0; j < 32; j++) { float ex = expf(ss[tid][j] - m); ss[tid][j] = ex; sm += ex; }
    rs[tid] = 1.0f / sm;
  }
  __syncthreads();
  {
    int idx = tid * 2;
    int i = idx >> 4, d = idx & 15;
    float a0 = 0, a1 = 0;
    for (int j = 0; j < 32; j++) { float wj = ss[i][j]; a0 += wj * vsh[j][d]; a1 += wj * vsh[j][d + 1]; }
    float r = rs[i];
    size_t base = ((size_t)(g * 32 + i)) * 128 + h * 16 + d;
    o[base] = a0 * r; o[base + 1] = a1 * r;
  }
}

// ---------------------------------------------------------------- seq attention body (L=128, SD=32)
__device__ __forceinline__ void sattn_body(
    int b, int h, int qt, const float* __restrict__ qkv, float* __restrict__ o)
{
  __shared__ float ks[128][33];
  __shared__ float vs[128][33];
  __shared__ float qs2[32][33];
  __shared__ float ss2[32][129];
  __shared__ float red[32][8];
  __shared__ float red2[32][8];
  const int tid = threadIdx.x;
  {
    int l = tid >> 1, d0 = (tid & 1) * 16;
    const float* kp = qkv + ((size_t)(b * 128 + l)) * 384 + 128 + h * 32 + d0;
    #pragma unroll
    for (int j = 0; j < 16; j++) { ks[l][d0 + j] = kp[j]; vs[l][d0 + j] = kp[128 + j]; }
  }
  {
    int i = tid >> 3, d0 = (tid & 7) * 4;
    const float* qp = qkv + ((size_t)(b * 128 + qt * 32 + i)) * 384 + h * 32 + d0;
    #pragma unroll
    for (int j = 0; j < 4; j++) qs2[i][d0 + j] = qp[j];
  }
  __syncthreads();
  const int i = tid >> 3, sub = tid & 7;
  {
    int j0 = sub * 16;
    for (int j = j0; j < j0 + 16; j++) {
      float a = 0;
      #pragma unroll
      for (int d = 0; d < 32; d++) a += qs2[i][d] * ks[j][d];
      ss2[i][j] = a * 0.17677669529663687f;
    }
  }
  __syncthreads();
  float m = -1e30f;
  for (int j = sub; j < 128; j += 8) m = fmaxf(m, ss2[i][j]);
  red[i][sub] = m;
  __syncthreads();
  float mm = red[i][0];
  #pragma unroll
  for (int t = 1; t < 8; t++) mm = fmaxf(mm, red[i][t]);
  float ps = 0;
  for (int j = sub; j < 128; j += 8) { float ex = expf(ss2[i][j] - mm); ss2[i][j] = ex; ps += ex; }
  red2[i][sub] = ps;
  __syncthreads();
  float sm = 0;
  #pragma unroll
  for (int t = 0; t < 8; t++) sm += red2[i][t];
  float rinv = 1.0f / sm;
  {
    int d0 = sub * 4;
    float a0 = 0, a1 = 0, a2 = 0, a3 = 0;
    for (int j = 0; j < 128; j++) {
      float wj = ss2[i][j];
      a0 += wj * vs[j][d0 + 0]; a1 += wj * vs[j][d0 + 1];
      a2 += wj * vs[j][d0 + 2]; a3 += wj * vs[j][d0 + 3];
    }
    float* op = o + ((size_t)(b * 128 + qt * 32 + i)) * 128 + h * 32 + d0;
    op[0] = a0 * rinv; op[1] = a1 * rinv; op[2] = a2 * rinv; op[3] = a3 * rinv;
  }
}

// ---------------------------------------------------------------- merged attention: graph 640 + seq 256
__global__ __launch_bounds__(256) void attn_k(
    int gBlocks, const float* q, const float* k, const float* v,
    const float* dist, float* go, const float* qkv, float* so)
{
  int bx = blockIdx.x;
  if (bx < gBlocks) gattn_body(bx >> 3, bx & 7, q, k, v, dist, go);
  else { int i = bx - gBlocks; sattn_body(i >> 4, (i >> 2) & 3, i & 3, qkv, so); }
}

// ---------------------------------------------------------------- layer tail body: x1=LN(A@Wo+bo+res); out=LN(relu(x1@W1+b1)@W2+b2+x1)
__device__ __forceinline__ void tail_body(
    int row0, const float* __restrict__ A,
    const float* __restrict__ Wo, const float* __restrict__ bo, const float* __restrict__ res,
    const float* __restrict__ g1, const float* __restrict__ b1n,
    const float* __restrict__ W1, const float* __restrict__ b1f,
    const float* __restrict__ W2, const float* __restrict__ b2f,
    const float* __restrict__ g2, const float* __restrict__ b2n,
    float* __restrict__ Out)
{
  __shared__ float x1[16][132];
  __shared__ float hid[16][260];
  __shared__ __align__(16) float sbuf[4352];
  __shared__ float Sa[32][20];
  float (*BsA)[136] = (float(*)[136])sbuf;
  float (*Bs1)[260] = (float(*)[260])sbuf;
  float (*Bs2)[136] = (float(*)[136])sbuf;
  const int tid = threadIdx.x;
  // ---- stage A: x1 = LN(A@Wo + bo + res) ----
  {
    const int tm = tid >> 5, tn = tid & 31;
    const int t0 = 2 * tm, e0 = 4 * tn;
    const int ar = tid >> 4, ak = (tid & 15) * 2;
    const int bk = tid >> 3, be = (tid & 7) * 16;
    float acc[2][4] = {};
    for (int k0 = 0; k0 < 128; k0 += 32) {
      float2 av = *(const float2*)(A + (size_t)(row0 + ar) * 128 + k0 + ak);
      Sa[ak][ar] = av.x; Sa[ak + 1][ar] = av.y;
      const float* bp = Wo + (size_t)(k0 + bk) * 128 + be;
      float4 b0v = *(const float4*)(bp + 0);
      float4 b1v = *(const float4*)(bp + 4);
      float4 b2v = *(const float4*)(bp + 8);
      float4 b3v = *(const float4*)(bp + 12);
      BsA[bk][be + 0] = b0v.x;  BsA[bk][be + 1] = b0v.y;  BsA[bk][be + 2] = b0v.z;  BsA[bk][be + 3] = b0v.w;
      BsA[bk][be + 4] = b1v.x;  BsA[bk][be + 5] = b1v.y;  BsA[bk][be + 6] = b1v.z;  BsA[bk][be + 7] = b1v.w;
      BsA[bk][be + 8] = b2v.x;  BsA[bk][be + 9] = b2v.y;  BsA[bk][be + 10] = b2v.z; BsA[bk][be + 11] = b2v.w;
      BsA[bk][be + 12] = b3v.x; BsA[bk][be + 13] = b3v.y; BsA[bk][be + 14] = b3v.z; BsA[bk][be + 15] = b3v.w;
      __syncthreads();
      #pragma unroll
      for (int kk = 0; kk < 32; kk++) {
        float2 a = *(const float2*)&Sa[kk][t0];
        float4 b = *(const float4*)&BsA[kk][e0];
        acc[0][0] += a.x * b.x; acc[0][1] += a.x * b.y; acc[0][2] += a.x * b.z; acc[0][3] += a.x * b.w;
        acc[1][0] += a.y * b.x; acc[1][1] += a.y * b.y; acc[1][2] += a.y * b.z; acc[1][3] += a.y * b.w;
      }
      __syncthreads();
    }
    #pragma unroll
    for (int i = 0; i < 2; i++) {
      int r = row0 + t0 + i;
      float v0 = acc[i][0] + bo[e0 + 0] + res[(size_t)r * 128 + e0 + 0];
      float v1 = acc[i][1] + bo[e0 + 1] + res[(size_t)r * 128 + e0 + 1];
      float v2 = acc[i][2] + bo[e0 + 2] + res[(size_t)r * 128 + e0 + 2];
      float v3 = acc[i][3] + bo[e0 + 3] + res[(size_t)r * 128 + e0 + 3];
      float s = v0 + v1 + v2 + v3;
      #pragma unroll
      for (int o = 1; o < 32; o <<= 1) s += __shfl_xor(s, o);
      float mean = s * (1.0f / 128.0f);
      float d0 = v0 - mean, d1 = v1 - mean, d2 = v2 - mean, d3 = v3 - mean;
      float sq = d0 * d0 + d1 * d1 + d2 * d2 + d3 * d3;
      #pragma unroll
      for (int o = 1; o < 32; o <<= 1) sq += __shfl_xor(sq, o);
      float rstd = 1.0f / sqrtf(sq * (1.0f / 128.0f) + 1e-5f);
      x1[t0 + i][e0 + 0] = d0 * rstd * g1[e0 + 0] + b1n[e0 + 0];
      x1[t0 + i][e0 + 1] = d1 * rstd * g1[e0 + 1] + b1n[e0 + 1];
      x1[t0 + i][e0 + 2] = d2 * rstd * g1[e0 + 2] + b1n[e0 + 2];
      x1[t0 + i][e0 + 3] = d3 * rstd * g1[e0 + 3] + b1n[e0 + 3];
    }
  }
  __syncthreads();
  // ---- stage B: hid = relu(x1 @ W1 + b1f), 16x256 ----
  {
    const int tm = tid >> 6, tn = tid & 63;
    const int t0 = 4 * tm, e0 = 4 * tn;
    const int ar = tid >> 4, ak = tid & 15;
    const int bk = tid >> 4, be = (tid & 15) * 16;
    float acc[4][4] = {};
    for (int k0 = 0; k0 < 128; k0 += 16) {
      Sa[ak][ar] = x1[ar][k0 + ak];
      const float* bp = W1 + (size_t)(k0 + bk) * 256 + be;
      float4 b0v = *(const float4*)(bp + 0);
      float4 b1v = *(const float4*)(bp + 4);
      float4 b2v = *(const float4*)(bp + 8);
      float4 b3v = *(const float4*)(bp + 12);
      Bs1[bk][be + 0] = b0v.x;  Bs1[bk][be + 1] = b0v.y;  Bs1[bk][be + 2] = b0v.z;  Bs1[bk][be + 3] = b0v.w;
      Bs1[bk][be + 4] = b1v.x;  Bs1[bk][be + 5] = b1v.y;  Bs1[bk][be + 6] = b1v.z;  Bs1[bk][be + 7] = b1v.w;
      Bs1[bk][be + 8] = b2v.x;  Bs1[bk][be + 9] = b2v.y;  Bs1[bk][be + 10] = b2v.z; Bs1[bk][be + 11] = b2v.w;
      Bs1[bk][be + 12] = b3v.x; Bs1[bk][be + 13] = b3v.y; Bs1[bk][be + 14] = b3v.z; Bs1[bk][be + 15] = b3v.w;
      __syncthreads();
      #pragma unroll
      for (int kk = 0; kk < 16; kk++) {
        float4 a = *(const float4*)&Sa[kk][t0];
        float4 b = *(const float4*)&Bs1[kk][e0];
        acc[0][0] += a.x * b.x; acc[0][1] += a.x * b.y; acc[0][2] += a.x * b.z; acc[0][3] += a.x * b.w;
        acc[1][0] += a.y * b.x; acc[1][1] += a.y * b.y; acc[1][2] += a.y * b.z; acc[1][3] += a.y * b.w;
        acc[2][0] += a.z * b.x; acc[2][1] += a.z * b.y; acc[2][2] += a.z * b.z; acc[2][3] += a.z * b.w;
        acc[3][0] += a.w * b.x; acc[3][1] += a.w * b.y; acc[3][2] += a.w * b.z; acc[3][3] += a.w * b.w;
      }
      __syncthreads();
    }
    #pragma unroll
    for (int i = 0; i < 4; i++) {
      float4 hv;
      hv.x = fmaxf(acc[i][0] + b1f[e0 + 0], 0.0f);
      hv.y = fmaxf(acc[i][1] + b1f[e0 + 1], 0.0f);
      hv.z = fmaxf(acc[i][2] + b1f[e0 + 2], 0.0f);
      hv.w = fmaxf(acc[i][3] + b1f[e0 + 3], 0.0f);
      *(float4*)&hid[t0 + i][e0] = hv;
    }
  }
  __syncthreads();
  // ---- stage C: Out = LN(hid@W2 + b2f + x1) ----
  {
    const int tm = tid >> 5, tn = tid & 31;
    const int t0 = 2 * tm, e0 = 4 * tn;
    const int bk = tid >> 3, be = (tid & 7) * 16;
    float acc[2][4] = {};
    for (int k0 = 0; k0 < 256; k0 += 32) {
      const float* bp = W2 + (size_t)(k0 + bk) * 128 + be;
      float4 b0v = *(const float4*)(bp + 0);
      float4 b1v = *(const float4*)(bp + 4);
      float4 b2v = *(const float4*)(bp + 8);
      float4 b3v = *(const float4*)(bp + 12);
      Bs2[bk][be + 0] = b0v.x;  Bs2[bk][be + 1] = b0v.y;  Bs2[bk][be + 2] = b0v.z;  Bs2[bk][be + 3] = b0v.w;
      Bs2[bk][be + 4] = b1v.x;  Bs2[bk][be + 5] = b1v.y;  Bs2[bk][be + 6] = b1v.z;  Bs2[bk][be + 7] = b1v.w;
      Bs2[bk][be + 8] = b2v.x;  Bs2[bk][be + 9] = b2v.y;  Bs2[bk][be + 10] = b2v.z; Bs2[bk][be + 11] = b2v.w;
      Bs2[bk][be + 12] = b3v.x; Bs2[bk][be + 13] = b3v.y; Bs2[bk][be + 14] = b3v.z; Bs2[bk][be + 15] = b3v.w;
      __syncthreads();
      #pragma unroll
      for (int kk = 0; kk < 32; kk++) {
        float a0 = hid[t0 + 0][k0 + kk];
        float a1 = hid[t0 + 1][k0 + kk];
        float4 b = *(const float4*)&Bs2[kk][e0];
        acc[0][0] += a0 * b.x; acc[0][1] += a0 * b.y; acc[0][2] += a0 * b.z; acc[0][3] += a0 * b.w;
        acc[1][0] += a1 * b.x; acc[1][1] += a1 * b.y; acc[1][2] += a1 * b.z; acc[1][3] += a1 * b.w;
      }
      __syncthreads();
    }
    #pragma unroll
    for (int i = 0; i < 2; i++) {
      int r = row0 + t0 + i;
      float v0 = acc[i][0] + b2f[e0 + 0] + x1[t0 + i][e0 + 0];
      float v1 = acc[i][1] + b2f[e0 + 1] + x1[t0 + i][e0 + 1];
      float v2 = acc[i][2] + b2f[e0 + 2] + x1[t0 + i][e0 + 2];
      float v3 = acc[i][3] + b2f[e0 + 3] + x1[t0 + i][e0 + 3];
      float s = v0 + v1 + v2 + v3;
      #pragma unroll
      for (int o = 1; o < 32; o <<= 1) s += __shfl_xor(s, o);
      float mean = s * (1.0f / 128.0f);
      float d0 = v0 - mean, d1 = v1 - mean, d2 = v2 - mean, d3 = v3 - mean;
      float sq = d0 * d0 + d1 * d1 + d2 * d2 + d3 * d3;
      #pragma unroll
      for (int o = 1; o < 32; o <<= 1) sq += __shfl_xor(sq, o);
      float rstd = 1.0f / sqrtf(sq * (1.0f / 128.0f) + 1e-5f);
      float* cp = Out + (size_t)r * 128 + e0;
      cp[0] = d0 * rstd * g2[e0 + 0] + b2n[e0 + 0];
      cp[1] = d1 * rstd * g2[e0 + 1] + b2n[e0 + 1];
      cp[2] = d2 * rstd * g2[e0 + 2] + b2n[e0 + 2];
      cp[3] = d3 * rstd * g2[e0 + 3] + b2n[e0 + 3];
    }
  }
}

// ---------------------------------------------------------------- merged tail: graph 160 + seq 128
__global__ __launch_bounds__(256) void tail_k(
    int gBlocks,
    const float* gA, const float* gWo, const float* gbo, const float* gres,
    const float* gg1, const float* gb1, const float* gW1, const float* gbf1,
    const float* gW2, const float* gbf2, const float* gg2, const float* gb2, float* gOut,
    const float* sA, const float* sWo, const float* sbo, const float* sres,
    const float* sg1, const float* sb1, const float* sW1, const float* sbf1,
    const float* sW2, const float* sbf2, const float* sg2, const float* sb2, float* sOut)
{
  int bx = blockIdx.x;
  if (bx < gBlocks)
    tail_body(bx * 16, gA, gWo, gbo, gres, gg1, gb1, gW1, gbf1, gW2, gbf2, gg2, gb2, gOut);
  else
    tail_body((bx - gBlocks) * 16, sA, sWo, sbo, sres, sg1, sb1, sW1, sbf1, sW2, sbf2, sg2, sb2, sOut);
}

// ---------------------------------------------------------------- LayerNorm rows of 128 (after edge aggr)
__global__ __launch_bounds__(128) void ln_k(
    const float* __restrict__ x, const float* __restrict__ res,
    const float* __restrict__ g, const float* __restrict__ b, float* __restrict__ out)
{
  __shared__ float sred[2];
  int r = blockIdx.x, e = threadIdx.x;
  size_t idx = (size_t)r * 128 + e;
  float v = x[idx] + res[idx];
  float nv = blk_norm(v, e, sred);
  out[idx] = nv * g[e] + b[e];
}

// ---------------------------------------------------------------- embedding
__global__ __launch_bounds__(128) void embed_k(
    const int* __restrict__ tokens, const float* __restrict__ tok_emb,
    const float* __restrict__ pos_emb, float* __restrict__ xs)
{
  int r = blockIdx.x, e = threadIdx.x;
  int tk = tokens[r];
  xs[(size_t)r * 128 + e] = tok_emb[(size_t)tk * 128 + e] + pos_emb[(size_t)(r & 127) * 128 + e];
}

// ---------------------------------------------------------------- pool + smean + fusion + cross-modal + head
__global__ __launch_bounds__(128) void head_k(
    const float* __restrict__ hb, const float* __restrict__ xs, const float* __restrict__ gfeat,
    const float* fg1w, const float* fg1b, const float* fg2w, const float* fg2b,
    const float* g2s_vw, const float* g2s_vb, const float* g2s_ow, const float* g2s_ob,
    const float* n1g, const float* n1b,
    const float* s2g_vw, const float* s2g_vb, const float* s2g_ow, const float* s2g_ob,
    const float* n2g, const float* n2b,
    const float* r1w, const float* r1b, const float* r2w, const float* r2b,
    float* __restrict__ out)
{
  __shared__ float T[128], S[128], G[128], Sm[128], t1[128], t2[128], gh[64], sred[2];
  int mol = blockIdx.x, e = threadIdx.x;
  {
    float cs = 0;
    for (int c = 0; c < 4; c++) {
      int g = mol * 4 + c;
      float s = 0;
      for (int i = 0; i < 32; i++) s += hb[((size_t)(g * 32 + i)) * 128 + e];
      cs += s * (1.0f / 32.0f);
    }
    cs *= 0.25f;
    float s2 = 0;
    int g = 64 + mol;
    for (int i = 0; i < 32; i++) s2 += hb[((size_t)(g * 32 + i)) * 128 + e];
    T[e] = cs + s2 * (1.0f / 32.0f);
    float ss = 0;
    for (int l = 0; l < 128; l++) ss += xs[((size_t)(mol * 128 + l)) * 128 + e];
    S[e] = ss * (1.0f / 128.0f);
  }
  __syncthreads();
  if (e < 64) {
    float a = fg1b[e];
    for (int f = 0; f < 128; f++) a += T[f] * fg1w[f * 64 + e];
    for (int f = 0; f < 128; f++) a += S[f] * fg1w[(128 + f) * 64 + e];
    gh[e] = fmaxf(a, 0.0f);
  }
  __syncthreads();
  {
    float a = fg2b[e];
    for (int j = 0; j < 64; j++) a += gh[j] * fg2w[j * 128 + e];
    float gate = 1.0f / (1.0f + expf(-a));
    float fu = gate * T[e] + (1.0f - gate) * S[e];
    G[e] = fu; Sm[e] = fu;
  }
  __syncthreads();
  for (int l = 0; l < 2; l++) {
    const float* vw = g2s_vw + (size_t)l * 16384; const float* vb = g2s_vb + l * 128;
    const float* ow = g2s_ow + (size_t)l * 16384; const float* ob = g2s_ob + l * 128;
    float a = vb[e];
    for (int f = 0; f < 128; f++) a += Sm[f] * vw[f * 128 + e];
    t1[e] = a;
    __syncthreads();
    a = ob[e];
    for (int f = 0; f < 128; f++) a += t1[f] * ow[f * 128 + e];
    float nv = blk_norm(G[e] + a, e, sred);
    G[e] = nv * n1g[l * 128 + e] + n1b[l * 128 + e];
    __syncthreads();
    const float* vw2 = s2g_vw + (size_t)l * 16384; const float* vb2 = s2g_vb + l * 128;
    const float* ow2 = s2g_ow + (size_t)l * 16384; const float* ob2 = s2g_ob + l * 128;
    a = vb2[e];
    for (int f = 0; f < 128; f++) a += G[f] * vw2[f * 128 + e];
    t1[e] = a;
    __syncthreads();
    a = ob2[e];
    for (int f = 0; f < 128; f++) a += t1[f] * ow2[f * 128 + e];
    nv = blk_norm(Sm[e] + a, e, sred);
    Sm[e] = nv * n2g[l * 128 + e] + n2b[l * 128 + e];
    __syncthreads();
  }
  t2[e] = 0.5f * (G[e] + Sm[e]);
  __syncthreads();
  float a = r1b[e];
  for (int f = 0; f < 128; f++) a += t2[f] * r1w[f * 128 + e];
  for (int f = 0; f < 3; f++) a += gfeat[mol * 3 + f] * r1w[(128 + f) * 128 + e];
  a = fmaxf(a, 0.0f);
  float p = a * r2w[e];
  #pragma unroll
  for (int o = 1; o < 64; o <<= 1) p += __shfl_xor(p, o);
  if ((e & 63) == 0) sred[e >> 6] = p;
  __syncthreads();
  if (e == 0) out[mol] = sred[0] + sred[1] + r2b[0];
}

// ================================================================ host
extern "C" void kernel_launch(void* const* d_in, const int* in_sizes, int n_in,
                              void* d_out, int out_size, void* d_ws, size_t ws_size,
                              hipStream_t stream)
{
  (void)n_in; (void)out_size; (void)ws_size;
  const bool dict = (in_sizes[1] == 8192);
  auto IN = [&](int di, int si) { return d_in[dict ? di : si]; };

  const float* conf_x   = (const float*)IN(0, 0);
  const int*   conf_ei  = (const int*)  IN(1, 63);
  const float* conf_ea  = (const float*)IN(2, 1);
  const float* conf_pos = (const float*)IN(3, 2);
  const float* scaf_x   = (const float*)IN(4, 3);
  const int*   scaf_ei  = (const int*)  IN(5, 64);
  const float* scaf_ea  = (const float*)IN(6, 4);
  const float* scaf_pos = (const float*)IN(7, 5);
  const int*   tokens   = (const int*)  IN(8, 65);
  const float* gfeat    = (const float*)IN(9, 6);
  const float* gproj_w  = (const float*)IN(11, 7);
  const float* gproj_b  = (const float*)IN(12, 8);
  const float* elin_w   = (const float*)IN(13, 9);
  const float* elin_b   = (const float*)IN(14, 10);
  const float* eln_g    = (const float*)IN(15, 11);
  const float* eln_b    = (const float*)IN(16, 12);
  const float* gt_qw    = (const float*)IN(17, 13);
  const float* gt_qb    = (const float*)IN(18, 14);
  const float* gt_kw    = (const float*)IN(19, 15);
  const float* gt_kb    = (const float*)IN(20, 16);
  const float* gt_vw    = (const float*)IN(21, 17);
  const float* gt_vb    = (const float*)IN(22, 18);
  const float* gt_ow    = (const float*)IN(23, 19);
  const float* gt_ob    = (const float*)IN(24, 20);
  const float* gt_ln1g  = (const float*)IN(25, 21);
  const float* gt_ln1b  = (const float*)IN(26, 22);
  const float* gt_f1w   = (const float*)IN(27, 23);
  const float* gt_f1b   = (const float*)IN(28, 24);
  const float* gt_f2w   = (const float*)IN(29, 25);
  const float* gt_f2b   = (const float*)IN(30, 26);
  const float* gt_ln2g  = (const float*)IN(31, 27);
  const float* gt_ln2b  = (const float*)IN(32, 28);
  const float* tok_emb  = (const float*)IN(33, 29);
  const float* pos_emb  = (const float*)IN(34, 30);
  const float* se_inw   = (const float*)IN(35, 31);
  const float* se_inb   = (const float*)IN(36, 32);
  const float* se_ow    = (const float*)IN(37, 33);
  const float* se_ob    = (const float*)IN(38, 34);
  const float* se_ln1g  = (const float*)IN(39, 35);
  const float* se_ln1b  = (const float*)IN(40, 36);
  const float* se_f1w   = (const float*)IN(41, 37);
  const float* se_f1b   = (const float*)IN(42, 38);
  const float* se_f2w   = (const float*)IN(43, 39);
  const float* se_f2b   = (const float*)IN(44, 40);
  const float* se_ln2g  = (const float*)IN(45, 41);
  const float* se_ln2b  = (const float*)IN(46, 42);
  const float* fg1_w    = (const float*)IN(47, 43);
  const float* fg1_b    = (const float*)IN(48, 44);
  const float* fg2_w    = (const float*)IN(49, 45);
  const float* fg2_b    = (const float*)IN(50, 46);
  const float* cm_g2s_vw = (const float*)IN(51, 47);
  const float* cm_g2s_vb = (const float*)IN(52, 48);
  const float* cm_g2s_ow = (const float*)IN(53, 49);
  const float* cm_g2s_ob = (const float*)IN(54, 50);
  const float* cm_s2g_vw = (const float*)IN(55, 53);
  const float* cm_s2g_vb = (const float*)IN(56, 54);
  const float* cm_s2g_ow = (const float*)IN(57, 55);
  const float* cm_s2g_ob = (const float*)IN(58, 56);
  const float* cm_n1g   = (const float*)IN(59, 51);
  const float* cm_n1b   = (const float*)IN(60, 52);
  const float* cm_n2g   = (const float*)IN(61, 57);
  const float* cm_n2b   = (const float*)IN(62, 58);
  const float* r1_w     = (const float*)IN(63, 59);
  const float* r1_b     = (const float*)IN(64, 60);
  const float* r2_w     = (const float*)IN(65, 61);
  const float* r2_b     = (const float*)IN(66, 62);
  float* out = (float*)d_out;

  // ---- workspace (fp32): graph & seq regions are DISJOINT (they now run concurrently) ----
  float* w = (float*)d_ws;
  size_t off = 0;
  auto alloc = [&](size_t n) { float* p = w + off; off += n; return p; };
  float* h     = alloc(2560 * 128);
  float* aggr  = alloc(2560 * 128);
  float* hb    = alloc(2560 * 128);
  float* distb = alloc(80 * 1024);
  float* qb    = alloc(3 * 327680);     // graph q/k/v
  float* atto  = alloc(327680);
  float* xs2   = alloc(2048 * 128);
  float* qkv3  = alloc(2048 * 384);
  float* satto = alloc(2048 * 128);
  float* xsfin = alloc(2048 * 128);

  // ============ graph front-end ============
  node_proj_k<<<2560, 128, 0, stream>>>(conf_x, scaf_x, gproj_w, gproj_b, h, aggr);
  dist_k<<<80, 256, 0, stream>>>(conf_pos, scaf_pos, distb);
  edge_gemm_k<<<dim3(80, 14), 256, 0, stream>>>(conf_ea, scaf_ea, conf_ei, scaf_ei, h, elin_w, elin_b, aggr);
  ln_k<<<2560, 128, 0, stream>>>(aggr, h, eln_g, eln_b, hb);
  embed_k<<<2048, 128, 0, stream>>>(tokens, tok_emb, pos_emb, xs2);

  // ============ merged graph(3) + seq(4) transformer layers ============
  for (int l = 0; l < 4; l++) {
    const bool hasG = (l < 3);
    const int lg = hasG ? l : 0;                  // keep pointers valid when unused
    const int gq = hasG ? 480 : 0;
    const int ga = hasG ? 640 : 0;
    const int gt = hasG ? 160 : 0;
    float* sOut = (l == 3) ? xsfin : xs2;
    qkv_k<<<gq + 384, 256, 0, stream>>>(gq,
        hb, gt_qw + (size_t)lg * 16384, gt_kw + (size_t)lg * 16384, gt_vw + (size_t)lg * 16384,
        gt_qb + lg * 128, gt_kb + lg * 128, gt_vb + lg * 128, qb,
        xs2, se_inw + (size_t)l * 49152, se_inb + l * 384, qkv3);
    attn_k<<<ga + 256, 256, 0, stream>>>(ga, qb, qb + 327680, qb + 655360, distb, atto, qkv3, satto);
    tail_k<<<gt + 128, 256, 0, stream>>>(gt,
        atto, gt_ow + (size_t)lg * 16384, gt_ob + lg * 128, hb,
        gt_ln1g + lg * 128, gt_ln1b + lg * 128,
        gt_f1w + (size_t)lg * 32768, gt_f1b + lg * 256,
        gt_f2w + (size_t)lg * 32768, gt_f2b + lg * 128,
        gt_ln2g + lg * 128, gt_ln2b + lg * 128, hb,
        satto, se_ow + (size_t)l * 16384, se_ob + l * 128, xs2,
        se_ln1g + l * 128, se_ln1b + l * 128,
        se_f1w + (size_t)l * 32768, se_f1b + l * 256,
        se_f2w + (size_t)l * 32768, se_f2b + l * 128,
        se_ln2g + l * 128, se_ln2b + l * 128, sOut);
  }

  // ============ pool + smean + fusion + cross-modal + regressor ============
  head_k<<<16, 128, 0, stream>>>(hb, xsfin, gfeat,
                                 fg1_w, fg1_b, fg2_w, fg2_b,
                                 cm_g2s_vw, cm_g2s_vb, cm_g2s_ow, cm_g2s_ob, cm_n1g, cm_n1b,
                                 cm_s2g_vw, cm_s2g_vb, cm_s2g_ow, cm_s2g_ob, cm_n2g, cm_n2b,
                                 r1_w, r1_b, r2_w, r2_b, out);
}

// Round 8
// 663.580 us; speedup vs baseline: 1.3643x; 1.3643x over previous
//
#include <hip/hip_runtime.h>
#include <hip/hip_bf16.h>

// E=128 GH=8 GD=16 GL=3 | SH=4 SD=32 SL=4 | N=32 GC=64 GS=16 DEG=64 BMOL=16
// M_conf=4096 M_scaf=1024 M_tot=5120. All float tensors fp32.

// ---------------------------------------------------------------- LN helper (block of 128 threads)
__device__ __forceinline__ float blk_norm(float v, int e, float* sred)
{
  float s = v;
  #pragma unroll
  for (int o = 1; o < 64; o <<= 1) s += __shfl_xor(s, o);
  if ((e & 63) == 0) sred[e >> 6] = s;
  __syncthreads();
  float mean = (sred[0] + sred[1]) * (1.0f / 128.0f);
  __syncthreads();
  float d = v - mean;
  float s2 = d * d;
  #pragma unroll
  for (int o = 1; o < 64; o <<= 1) s2 += __shfl_xor(s2, o);
  if ((e & 63) == 0) sred[e >> 6] = s2;
  __syncthreads();
  float var = (sred[0] + sred[1]) * (1.0f / 128.0f);
  __syncthreads();
  return d / sqrtf(var + 1e-5f);
}

// ---------------------------------------------------------------- node projection (+ zero aggr)
__global__ __launch_bounds__(128) void node_proj_k(
    const float* __restrict__ cx, const float* __restrict__ sx,
    const float* __restrict__ w, const float* __restrict__ b,
    float* __restrict__ h, float* __restrict__ aggr)
{
  int r = blockIdx.x, e = threadIdx.x;
  const float* x = (r < 2048) ? (cx + (size_t)r * 64) : (sx + (size_t)(r - 2048) * 64);
  __shared__ float xs[64];
  if (e < 64) xs[e] = x[e];
  __syncthreads();
  float acc = b[e];
  for (int a = 0; a < 64; a++) acc += xs[a] * w[a * 128 + e];
  h[(size_t)r * 128 + e] = acc;
  aggr[(size_t)r * 128 + e] = 0.0f;
}

// ---------------------------------------------------------------- pairwise distance per graph
__global__ __launch_bounds__(256) void dist_k(
    const float* __restrict__ cpos, const float* __restrict__ spos, float* __restrict__ dist)
{
  int g = blockIdx.x, tid = threadIdx.x;
  __shared__ float P[96];
  const float* p = (g < 64) ? (cpos + (size_t)g * 96) : (spos + (size_t)(g - 64) * 96);
  if (tid < 96) P[tid] = p[tid];
  __syncthreads();
  #pragma unroll
  for (int jj = 0; jj < 4; jj++) {
    int idx = tid * 4 + jj;
    int i = idx >> 5, j = idx & 31;
    float dx = P[i * 3 + 0] - P[j * 3 + 0];
    float dy = P[i * 3 + 1] - P[j * 3 + 1];
    float dz = P[i * 3 + 2] - P[j * 3 + 2];
    float d2 = dx * dx + dy * dy + dz * dz;
    dist[(size_t)g * 1024 + idx] = (d2 > 0.0f) ? sqrtf(d2) : 0.0f;
  }
}

// ---------------------------------------------------------------- EdgeNetwork GEMM + atomic scatter
// 32-edge tile x 28-kt chunk (exactly 7 c's). hd held in REGISTERS (each As-gen thread
// needs only h[dst][f0+gk] for f0 in {0,32,64,96} -- same 4 values for every c).
// LDS ~23KB -> 7 blocks/CU. grid (160, 7).
__global__ __launch_bounds__(256) void edge_gemm_k(
    const float* __restrict__ cea, const float* __restrict__ sea,
    const int* __restrict__ cei, const int* __restrict__ sei,
    const float* __restrict__ h,
    const float* __restrict__ elw, const float* __restrict__ elb,
    float* __restrict__ aggr)
{
  __shared__ float efs[32][8];
  __shared__ float As[32][36];     // As[k][edge], 144B rows (16B-aligned)
  __shared__ float Bs[32][136];    // Bs[k][e]
  const int tid = threadIdx.x;
  const int m0 = blockIdx.x * 32;
  const int kt0 = blockIdx.y * 28;
  const int c0 = kt0 >> 2;         // 28 kts = exactly c0..c0+6
  // ---- edge features for the 7 c's this chunk needs ----
  {
    int t = tid >> 3, cc = tid & 7;
    if (cc < 7) {
      int c = c0 + cc;
      int m = m0 + t;
      const float* attr = (m < 4096) ? (cea + (size_t)m * 17) : (sea + (size_t)(m - 4096) * 17);
      float val;
      if (c < 16) val = attr[c];
      else if (c < 48) {
        float d = fminf(fmaxf(attr[16], 0.0f), 10.0f);
        float t2 = d - (float)((c - 16) * (5.0 / 31.0));
        val = expf(-38.44f * t2 * t2);           // gamma = (31/5)^2
      } else val = 1.0f;
      efs[t][cc] = val;
    }
  }
  // ---- per-thread register copy of the h values this thread's As entries need ----
  const int gk = tid & 31, gt = (tid >> 5) * 4;
  float hreg[4][4];
  #pragma unroll
  for (int i = 0; i < 4; i++) {
    int m = m0 + gt + i;
    int dst = (m < 4096) ? cei[4096 + m] : (sei[1024 + (m - 4096)] + 2048);
    const float* hp = h + (size_t)dst * 128 + gk;
    hreg[i][0] = hp[0]; hreg[i][1] = hp[32]; hreg[i][2] = hp[64]; hreg[i][3] = hp[96];
  }
  const int tn = tid & 31, tm = tid >> 5;
  const int e0 = 4 * tn, t0 = 4 * tm;
  const int se = tid >> 1, sk = (tid & 1) * 16;
  float acc[4][4] = {};
  __syncthreads();
  #pragma unroll 1
  for (int kt = kt0; kt < kt0 + 28; kt++) {
    int c = kt >> 2, cc = c - c0, j = kt & 3;
    float4 av;
    av.x = efs[gt + 0][cc] * hreg[0][j];
    av.y = efs[gt + 1][cc] * hreg[1][j];
    av.z = efs[gt + 2][cc] * hreg[2][j];
    av.w = efs[gt + 3][cc] * hreg[3][j];
    *(float4*)&As[gk][gt] = av;
    const float* bp = ((c < 48) ? (elw + (size_t)c * 16384) : elb) + (size_t)se * 128 + j * 32 + sk;
    float4 w0 = *(const float4*)(bp + 0);
    float4 w1 = *(const float4*)(bp + 4);
    float4 w2 = *(const float4*)(bp + 8);
    float4 w3 = *(const float4*)(bp + 12);
    Bs[sk + 0][se] = w0.x;  Bs[sk + 1][se] = w0.y;  Bs[sk + 2][se] = w0.z;  Bs[sk + 3][se] = w0.w;
    Bs[sk + 4][se] = w1.x;  Bs[sk + 5][se] = w1.y;  Bs[sk + 6][se] = w1.z;  Bs[sk + 7][se] = w1.w;
    Bs[sk + 8][se] = w2.x;  Bs[sk + 9][se] = w2.y;  Bs[sk + 10][se] = w2.z; Bs[sk + 11][se] = w2.w;
    Bs[sk + 12][se] = w3.x; Bs[sk + 13][se] = w3.y; Bs[sk + 14][se] = w3.z; Bs[sk + 15][se] = w3.w;
    __syncthreads();
    #pragma unroll
    for (int kk = 0; kk < 32; kk++) {
      float4 a = *(const float4*)&As[kk][t0];
      float4 b = *(const float4*)&Bs[kk][e0];
      acc[0][0] += a.x * b.x; acc[0][1] += a.x * b.y; acc[0][2] += a.x * b.z; acc[0][3] += a.x * b.w;
      acc[1][0] += a.y * b.x; acc[1][1] += a.y * b.y; acc[1][2] += a.y * b.z; acc[1][3] += a.y * b.w;
      acc[2][0] += a.z * b.x; acc[2][1] += a.z * b.y; acc[2][2] += a.z * b.z; acc[2][3] += a.z * b.w;
      acc[3][0] += a.w * b.x; acc[3][1] += a.w * b.y; acc[3][2] += a.w * b.z; acc[3][3] += a.w * b.w;
    }
    __syncthreads();
  }
  #pragma unroll
  for (int i = 0; i < 4; i++) {
    int m = m0 + t0 + i;
    int src = (m < 4096) ? cei[m] : (sei[m - 4096] + 2048);
    float* dst = aggr + (size_t)src * 128 + e0;
    atomicAdd(dst + 0, acc[i][0]);
    atomicAdd(dst + 1, acc[i][1]);
    atomicAdd(dst + 2, acc[i][2]);
    atomicAdd(dst + 3, acc[i][3]);
  }
}

// ---------------------------------------------------------------- BM=16 GEMM body: Cp = A@Bp + biasp (K=128)
__device__ __forceinline__ void gemm16_body(
    const float* __restrict__ A, const float* __restrict__ Bp,
    const float* __restrict__ biasp, float* __restrict__ Cp,
    int row0, int ldb, int ldc)
{
  __shared__ float Sa[32][20];
  __shared__ float Bs[32][136];
  const int tid = threadIdx.x;
  const int tm = tid >> 5, tn = tid & 31;
  const int t0 = 2 * tm, e0 = 4 * tn;
  const int ar = tid >> 4, ak = (tid & 15) * 2;
  const int bk = tid >> 3, be = (tid & 7) * 16;
  float acc[2][4] = {};
  for (int k0 = 0; k0 < 128; k0 += 32) {
    float2 av = *(const float2*)(A + (size_t)(row0 + ar) * 128 + k0 + ak);
    Sa[ak][ar] = av.x; Sa[ak + 1][ar] = av.y;
    const float* bp = Bp + (size_t)(k0 + bk) * ldb + be;
    float4 b0v = *(const float4*)(bp + 0);
    float4 b1v = *(const float4*)(bp + 4);
    float4 b2v = *(const float4*)(bp + 8);
    float4 b3v = *(const float4*)(bp + 12);
    Bs[bk][be + 0] = b0v.x;  Bs[bk][be + 1] = b0v.y;  Bs[bk][be + 2] = b0v.z;  Bs[bk][be + 3] = b0v.w;
    Bs[bk][be + 4] = b1v.x;  Bs[bk][be + 5] = b1v.y;  Bs[bk][be + 6] = b1v.z;  Bs[bk][be + 7] = b1v.w;
    Bs[bk][be + 8] = b2v.x;  Bs[bk][be + 9] = b2v.y;  Bs[bk][be + 10] = b2v.z; Bs[bk][be + 11] = b2v.w;
    Bs[bk][be + 12] = b3v.x; Bs[bk][be + 13] = b3v.y; Bs[bk][be + 14] = b3v.z; Bs[bk][be + 15] = b3v.w;
    __syncthreads();
    #pragma unroll
    for (int kk = 0; kk < 32; kk++) {
      float2 a = *(const float2*)&Sa[kk][t0];
      float4 b = *(const float4*)&Bs[kk][e0];
      acc[0][0] += a.x * b.x; acc[0][1] += a.x * b.y; acc[0][2] += a.x * b.z; acc[0][3] += a.x * b.w;
      acc[1][0] += a.y * b.x; acc[1][1] += a.y * b.y; acc[1][2] += a.y * b.z; acc[1][3] += a.y * b.w;
    }
    __syncthreads();
  }
  #pragma unroll
  for (int i = 0; i < 2; i++) {
    float* cp = Cp + (size_t)(row0 + t0 + i) * ldc + e0;
    #pragma unroll
    for (int j = 0; j < 4; j++) cp[j] = acc[i][j] + biasp[e0 + j];
  }
}

// ---------------------------------------------------------------- merged QKV: graph (3x160) + seq (3x128)
__global__ __launch_bounds__(256) void qkv_k(
    int gBlocks,
    const float* __restrict__ ghb,
    const float* gqw, const float* gkw, const float* gvw,
    const float* gqb, const float* gkb, const float* gvb, float* gout,
    const float* __restrict__ sxs, const float* sw, const float* sb, float* sout)
{
  int bx = blockIdx.x;
  if (bx < gBlocks) {
    int z = bx / 160, rt = bx % 160;
    const float* B = (z == 0) ? gqw : (z == 1) ? gkw : gvw;
    const float* bias = (z == 0) ? gqb : (z == 1) ? gkb : gvb;
    gemm16_body(ghb, B, bias, gout + (size_t)z * 327680, rt * 16, 128, 128);
  } else {
    int i = bx - gBlocks;
    int z = i >> 7, rt = i & 127;
    gemm16_body(sxs, sw + z * 128, sb + z * 128, sout + z * 128, rt * 16, 384, 384);
  }
}

// ---------------------------------------------------------------- graph attention body (N=32, GD=16)
__device__ __forceinline__ void gattn_body(
    int g, int h, const float* __restrict__ q, const float* __restrict__ k,
    const float* __restrict__ v, const float* __restrict__ dist, float* __restrict__ o)
{
  __shared__ float qs[32][17], ksh[32][17], vsh[32][17], ss[32][33], rs[32];
  const int tid = threadIdx.x;
  {
    int idx = tid * 2;
    int i = idx >> 4, d = idx & 15;
    size_t base = ((size_t)(g * 32 + i)) * 128 + h * 16 + d;
    qs[i][d] = q[base];  qs[i][d + 1] = q[base + 1];
    ksh[i][d] = k[base]; ksh[i][d + 1] = k[base + 1];
    vsh[i][d] = v[base]; vsh[i][d + 1] = v[base + 1];
  }
  __syncthreads();
  {
    int i = tid >> 3, j0 = (tid & 7) * 4;
    for (int j = j0; j < j0 + 4; j++) {
      float a = 0;
      #pragma unroll
      for (int d = 0; d < 16; d++) a += qs[i][d] * ksh[j][d];
      a = a * 0.25f + dist[(size_t)g * 1024 + i * 32 + j];
      ss[i][j] = fminf(fmaxf(a, -10.0f), 10.0f);
    }
  }
  __syncthreads();
  if (tid < 32) {
    float m = -1e30f;
    for (int j = 0; j < 32; j++) m = fmaxf(m, ss[tid][j]);
    float sm = 0;
    for (int j = 0; j < 32; j++) { float ex = expf(ss[tid][j] - m); ss[tid][j] = ex; sm += ex; }
    rs[tid] = 1.0f / sm;
  }
  __syncthreads();
  {
    int idx = tid * 2;
    int i = idx >> 4, d = idx & 15;
    float a0 = 0, a1 = 0;
    for (int j = 0; j < 32; j++) { float wj = ss[i][j]; a0 += wj * vsh[j][d]; a1 += wj * vsh[j][d + 1]; }
    float r = rs[i];
    size_t base = ((size_t)(g * 32 + i)) * 128 + h * 16 + d;
    o[base] = a0 * r; o[base + 1] = a1 * r;
  }
}

// ---------------------------------------------------------------- seq attention body (L=128, SD=32)
__device__ __forceinline__ void sattn_body(
    int b, int h, int qt, const float* __restrict__ qkv, float* __restrict__ o)
{
  __shared__ float ks[128][33];
  __shared__ float vs[128][33];
  __shared__ float qs2[32][33];
  __shared__ float ss2[32][129];
  __shared__ float red[32][8];
  __shared__ float red2[32][8];
  const int tid = threadIdx.x;
  {
    int l = tid >> 1, d0 = (tid & 1) * 16;
    const float* kp = qkv + ((size_t)(b * 128 + l)) * 384 + 128 + h * 32 + d0;
    #pragma unroll
    for (int j = 0; j < 16; j++) { ks[l][d0 + j] = kp[j]; vs[l][d0 + j] = kp[128 + j]; }
  }
  {
    int i = tid >> 3, d0 = (tid & 7) * 4;
    const float* qp = qkv + ((size_t)(b * 128 + qt * 32 + i)) * 384 + h * 32 + d0;
    #pragma unroll
    for (int j = 0; j < 4; j++) qs2[i][d0 + j] = qp[j];
  }
  __syncthreads();
  const int i = tid >> 3, sub = tid & 7;
  {
    int j0 = sub * 16;
    for (int j = j0; j < j0 + 16; j++) {
      float a = 0;
      #pragma unroll
      for (int d = 0; d < 32; d++) a += qs2[i][d] * ks[j][d];
      ss2[i][j] = a * 0.17677669529663687f;
    }
  }
  __syncthreads();
  float m = -1e30f;
  for (int j = sub; j < 128; j += 8) m = fmaxf(m, ss2[i][j]);
  red[i][sub] = m;
  __syncthreads();
  float mm = red[i][0];
  #pragma unroll
  for (int t = 1; t < 8; t++) mm = fmaxf(mm, red[i][t]);
  float ps = 0;
  for (int j = sub; j < 128; j += 8) { float ex = expf(ss2[i][j] - mm); ss2[i][j] = ex; ps += ex; }
  red2[i][sub] = ps;
  __syncthreads();
  float sm = 0;
  #pragma unroll
  for (int t = 0; t < 8; t++) sm += red2[i][t];
  float rinv = 1.0f / sm;
  {
    int d0 = sub * 4;
    float a0 = 0, a1 = 0, a2 = 0, a3 = 0;
    for (int j = 0; j < 128; j++) {
      float wj = ss2[i][j];
      a0 += wj * vs[j][d0 + 0]; a1 += wj * vs[j][d0 + 1];
      a2 += wj * vs[j][d0 + 2]; a3 += wj * vs[j][d0 + 3];
    }
    float* op = o + ((size_t)(b * 128 + qt * 32 + i)) * 128 + h * 32 + d0;
    op[0] = a0 * rinv; op[1] = a1 * rinv; op[2] = a2 * rinv; op[3] = a3 * rinv;
  }
}

// ---------------------------------------------------------------- merged attention: graph 640 + seq 256
__global__ __launch_bounds__(256) void attn_k(
    int gBlocks, const float* q, const float* k, const float* v,
    const float* dist, float* go, const float* qkv, float* so)
{
  int bx = blockIdx.x;
  if (bx < gBlocks) gattn_body(bx >> 3, bx & 7, q, k, v, dist, go);
  else { int i = bx - gBlocks; sattn_body(i >> 4, (i >> 2) & 3, i & 3, qkv, so); }
}

// ---------------------------------------------------------------- layer tail body: x1=LN(A@Wo+bo+res); out=LN(relu(x1@W1+b1)@W2+b2+x1)
__device__ __forceinline__ void tail_body(
    int row0, const float* __restrict__ A,
    const float* __restrict__ Wo, const float* __restrict__ bo, const float* __restrict__ res,
    const float* __restrict__ g1, const float* __restrict__ b1n,
    const float* __restrict__ W1, const float* __restrict__ b1f,
    const float* __restrict__ W2, const float* __restrict__ b2f,
    const float* __restrict__ g2, const float* __restrict__ b2n,
    float* __restrict__ Out)
{
  __shared__ float x1[16][132];
  __shared__ float hid[16][260];
  __shared__ __align__(16) float sbuf[4352];
  __shared__ float Sa[32][20];
  float (*BsA)[136] = (float(*)[136])sbuf;
  float (*Bs1)[260] = (float(*)[260])sbuf;
  float (*Bs2)[136] = (float(*)[136])sbuf;
  const int tid = threadIdx.x;
  // ---- stage A: x1 = LN(A@Wo + bo + res) ----
  {
    const int tm = tid >> 5, tn = tid & 31;
    const int t0 = 2 * tm, e0 = 4 * tn;
    const int ar = tid >> 4, ak = (tid & 15) * 2;
    const int bk = tid >> 3, be = (tid & 7) * 16;
    float acc[2][4] = {};
    for (int k0 = 0; k0 < 128; k0 += 32) {
      float2 av = *(const float2*)(A + (size_t)(row0 + ar) * 128 + k0 + ak);
      Sa[ak][ar] = av.x; Sa[ak + 1][ar] = av.y;
      const float* bp = Wo + (size_t)(k0 + bk) * 128 + be;
      float4 b0v = *(const float4*)(bp + 0);
      float4 b1v = *(const float4*)(bp + 4);
      float4 b2v = *(const float4*)(bp + 8);
      float4 b3v = *(const float4*)(bp + 12);
      BsA[bk][be + 0] = b0v.x;  BsA[bk][be + 1] = b0v.y;  BsA[bk][be + 2] = b0v.z;  BsA[bk][be + 3] = b0v.w;
      BsA[bk][be + 4] = b1v.x;  BsA[bk][be + 5] = b1v.y;  BsA[bk][be + 6] = b1v.z;  BsA[bk][be + 7] = b1v.w;
      BsA[bk][be + 8] = b2v.x;  BsA[bk][be + 9] = b2v.y;  BsA[bk][be + 10] = b2v.z; BsA[bk][be + 11] = b2v.w;
      BsA[bk][be + 12] = b3v.x; BsA[bk][be + 13] = b3v.y; BsA[bk][be + 14] = b3v.z; BsA[bk][be + 15] = b3v.w;
      __syncthreads();
      #pragma unroll
      for (int kk = 0; kk < 32; kk++) {
        float2 a = *(const float2*)&Sa[kk][t0];
        float4 b = *(const float4*)&BsA[kk][e0];
        acc[0][0] += a.x * b.x; acc[0][1] += a.x * b.y; acc[0][2] += a.x * b.z; acc[0][3] += a.x * b.w;
        acc[1][0] += a.y * b.x; acc[1][1] += a.y * b.y; acc[1][2] += a.y * b.z; acc[1][3] += a.y * b.w;
      }
      __syncthreads();
    }
    #pragma unroll
    for (int i = 0; i < 2; i++) {
      int r = row0 + t0 + i;
      float v0 = acc[i][0] + bo[e0 + 0] + res[(size_t)r * 128 + e0 + 0];
      float v1 = acc[i][1] + bo[e0 + 1] + res[(size_t)r * 128 + e0 + 1];
      float v2 = acc[i][2] + bo[e0 + 2] + res[(size_t)r * 128 + e0 + 2];
      float v3 = acc[i][3] + bo[e0 + 3] + res[(size_t)r * 128 + e0 + 3];
      float s = v0 + v1 + v2 + v3;
      #pragma unroll
      for (int o = 1; o < 32; o <<= 1) s += __shfl_xor(s, o);
      float mean = s * (1.0f / 128.0f);
      float d0 = v0 - mean, d1 = v1 - mean, d2 = v2 - mean, d3 = v3 - mean;
      float sq = d0 * d0 + d1 * d1 + d2 * d2 + d3 * d3;
      #pragma unroll
      for (int o = 1; o < 32; o <<= 1) sq += __shfl_xor(sq, o);
      float rstd = 1.0f / sqrtf(sq * (1.0f / 128.0f) + 1e-5f);
      x1[t0 + i][e0 + 0] = d0 * rstd * g1[e0 + 0] + b1n[e0 + 0];
      x1[t0 + i][e0 + 1] = d1 * rstd * g1[e0 + 1] + b1n[e0 + 1];
      x1[t0 + i][e0 + 2] = d2 * rstd * g1[e0 + 2] + b1n[e0 + 2];
      x1[t0 + i][e0 + 3] = d3 * rstd * g1[e0 + 3] + b1n[e0 + 3];
    }
  }
  __syncthreads();
  // ---- stage B: hid = relu(x1 @ W1 + b1f), 16x256 ----
  {
    const int tm = tid >> 6, tn = tid & 63;
    const int t0 = 4 * tm, e0 = 4 * tn;
    const int ar = tid >> 4, ak = tid & 15;
    const int bk = tid >> 4, be = (tid & 15) * 16;
    float acc[4][4] = {};
    for (int k0 = 0; k0 < 128; k0 += 16) {
      Sa[ak][ar] = x1[ar][k0 + ak];
      const float* bp = W1 + (size_t)(k0 + bk) * 256 + be;
      float4 b0v = *(const float4*)(bp + 0);
      float4 b1v = *(const float4*)(bp + 4);
      float4 b2v = *(const float4*)(bp + 8);
      float4 b3v = *(const float4*)(bp + 12);
      Bs1[bk][be + 0] = b0v.x;  Bs1[bk][be + 1] = b0v.y;  Bs1[bk][be + 2] = b0v.z;  Bs1[bk][be + 3] = b0v.w;
      Bs1[bk][be + 4] = b1v.x;  Bs1[bk][be + 5] = b1v.y;  Bs1[bk][be + 6] = b1v.z;  Bs1[bk][be + 7] = b1v.w;
      Bs1[bk][be + 8] = b2v.x;  Bs1[bk][be + 9] = b2v.y;  Bs1[bk][be + 10] = b2v.z; Bs1[bk][be + 11] = b2v.w;
      Bs1[bk][be + 12] = b3v.x; Bs1[bk][be + 13] = b3v.y; Bs1[bk][be + 14] = b3v.z; Bs1[bk][be + 15] = b3v.w;
      __syncthreads();
      #pragma unroll
      for (int kk = 0; kk < 16; kk++) {
        float4 a = *(const float4*)&Sa[kk][t0];
        float4 b = *(const float4*)&Bs1[kk][e0];
        acc[0][0] += a.x * b.x; acc[0][1] += a.x * b.y; acc[0][2] += a.x * b.z; acc[0][3] += a.x * b.w;
        acc[1][0] += a.y * b.x; acc[1][1] += a.y * b.y; acc[1][2] += a.y * b.z; acc[1][3] += a.y * b.w;
        acc[2][0] += a.z * b.x; acc[2][1] += a.z * b.y; acc[2][2] += a.z * b.z; acc[2][3] += a.z * b.w;
        acc[3][0] += a.w * b.x; acc[3][1] += a.w * b.y; acc[3][2] += a.w * b.z; acc[3][3] += a.w * b.w;
      }
      __syncthreads();
    }
    #pragma unroll
    for (int i = 0; i < 4; i++) {
      float4 hv;
      hv.x = fmaxf(acc[i][0] + b1f[e0 + 0], 0.0f);
      hv.y = fmaxf(acc[i][1] + b1f[e0 + 1], 0.0f);
      hv.z = fmaxf(acc[i][2] + b1f[e0 + 2], 0.0f);
      hv.w = fmaxf(acc[i][3] + b1f[e0 + 3], 0.0f);
      *(float4*)&hid[t0 + i][e0] = hv;
    }
  }
  __syncthreads();
  // ---- stage C: Out = LN(hid@W2 + b2f + x1) ----
  {
    const int tm = tid >> 5, tn = tid & 31;
    const int t0 = 2 * tm, e0 = 4 * tn;
    const int bk = tid >> 3, be = (tid & 7) * 16;
    float acc[2][4] = {};
    for (int k0 = 0; k0 < 256; k0 += 32) {
      const float* bp = W2 + (size_t)(k0 + bk) * 128 + be;
      float4 b0v = *(const float4*)(bp + 0);
      float4 b1v = *(const float4*)(bp + 4);
      float4 b2v = *(const float4*)(bp + 8);
      float4 b3v = *(const float4*)(bp + 12);
      Bs2[bk][be + 0] = b0v.x;  Bs2[bk][be + 1] = b0v.y;  Bs2[bk][be + 2] = b0v.z;  Bs2[bk][be + 3] = b0v.w;
      Bs2[bk][be + 4] = b1v.x;  Bs2[bk][be + 5] = b1v.y;  Bs2[bk][be + 6] = b1v.z;  Bs2[bk][be + 7] = b1v.w;
      Bs2[bk][be + 8] = b2v.x;  Bs2[bk][be + 9] = b2v.y;  Bs2[bk][be + 10] = b2v.z; Bs2[bk][be + 11] = b2v.w;
      Bs2[bk][be + 12] = b3v.x; Bs2[bk][be + 13] = b3v.y; Bs2[bk][be + 14] = b3v.z; Bs2[bk][be + 15] = b3v.w;
      __syncthreads();
      #pragma unroll
      for (int kk = 0; kk < 32; kk++) {
        float a0 = hid[t0 + 0][k0 + kk];
        float a1 = hid[t0 + 1][k0 + kk];
        float4 b = *(const float4*)&Bs2[kk][e0];
        acc[0][0] += a0 * b.x; acc[0][1] += a0 * b.y; acc[0][2] += a0 * b.z; acc[0][3] += a0 * b.w;
        acc[1][0] += a1 * b.x; acc[1][1] += a1 * b.y; acc[1][2] += a1 * b.z; acc[1][3] += a1 * b.w;
      }
      __syncthreads();
    }
    #pragma unroll
    for (int i = 0; i < 2; i++) {
      int r = row0 + t0 + i;
      float v0 = acc[i][0] + b2f[e0 + 0] + x1[t0 + i][e0 + 0];
      float v1 = acc[i][1] + b2f[e0 + 1] + x1[t0 + i][e0 + 1];
      float v2 = acc[i][2] + b2f[e0 + 2] + x1[t0 + i][e0 + 2];
      float v3 = acc[i][3] + b2f[e0 + 3] + x1[t0 + i][e0 + 3];
      float s = v0 + v1 + v2 + v3;
      #pragma unroll
      for (int o = 1; o < 32; o <<= 1) s += __shfl_xor(s, o);
      float mean = s * (1.0f / 128.0f);
      float d0 = v0 - mean, d1 = v1 - mean, d2 = v2 - mean, d3 = v3 - mean;
      float sq = d0 * d0 + d1 * d1 + d2 * d2 + d3 * d3;
      #pragma unroll
      for (int o = 1; o < 32; o <<= 1) sq += __shfl_xor(sq, o);
      float rstd = 1.0f / sqrtf(sq * (1.0f / 128.0f) + 1e-5f);
      float* cp = Out + (size_t)r * 128 + e0;
      cp[0] = d0 * rstd * g2[e0 + 0] + b2n[e0 + 0];
      cp[1] = d1 * rstd * g2[e0 + 1] + b2n[e0 + 1];
      cp[2] = d2 * rstd * g2[e0 + 2] + b2n[e0 + 2];
      cp[3] = d3 * rstd * g2[e0 + 3] + b2n[e0 + 3];
    }
  }
}

// ---------------------------------------------------------------- merged tail: graph 160 + seq 128
__global__ __launch_bounds__(256) void tail_k(
    int gBlocks,
    const float* gA, const float* gWo, const float* gbo, const float* gres,
    const float* gg1, const float* gb1, const float* gW1, const float* gbf1,
    const float* gW2, const float* gbf2, const float* gg2, const float* gb2, float* gOut,
    const float* sA, const float* sWo, const float* sbo, const float* sres,
    const float* sg1, const float* sb1, const float* sW1, const float* sbf1,
    const float* sW2, const float* sbf2, const float* sg2, const float* sb2, float* sOut)
{
  int bx = blockIdx.x;
  if (bx < gBlocks)
    tail_body(bx * 16, gA, gWo, gbo, gres, gg1, gb1, gW1, gbf1, gW2, gbf2, gg2, gb2, gOut);
  else
    tail_body((bx - gBlocks) * 16, sA, sWo, sbo, sres, sg1, sb1, sW1, sbf1, sW2, sbf2, sg2, sb2, sOut);
}

// ---------------------------------------------------------------- LayerNorm rows of 128 (after edge aggr)
__global__ __launch_bounds__(128) void ln_k(
    const float* __restrict__ x, const float* __restrict__ res,
    const float* __restrict__ g, const float* __restrict__ b, float* __restrict__ out)
{
  __shared__ float sred[2];
  int r = blockIdx.x, e = threadIdx.x;
  size_t idx = (size_t)r * 128 + e;
  float v = x[idx] + res[idx];
  float nv = blk_norm(v, e, sred);
  out[idx] = nv * g[e] + b[e];
}

// ---------------------------------------------------------------- embedding
__global__ __launch_bounds__(128) void embed_k(
    const int* __restrict__ tokens, const float* __restrict__ tok_emb,
    const float* __restrict__ pos_emb, float* __restrict__ xs)
{
  int r = blockIdx.x, e = threadIdx.x;
  int tk = tokens[r];
  xs[(size_t)r * 128 + e] = tok_emb[(size_t)tk * 128 + e] + pos_emb[(size_t)(r & 127) * 128 + e];
}

// ---------------------------------------------------------------- pool + smean + fusion + cross-modal + head
__global__ __launch_bounds__(128) void head_k(
    const float* __restrict__ hb, const float* __restrict__ xs, const float* __restrict__ gfeat,
    const float* fg1w, const float* fg1b, const float* fg2w, const float* fg2b,
    const float* g2s_vw, const float* g2s_vb, const float* g2s_ow, const float* g2s_ob,
    const float* n1g, const float* n1b,
    const float* s2g_vw, const float* s2g_vb, const float* s2g_ow, const float* s2g_ob,
    const float* n2g, const float* n2b,
    const float* r1w, const float* r1b, const float* r2w, const float* r2b,
    float* __restrict__ out)
{
  __shared__ float T[128], S[128], G[128], Sm[128], t1[128], t2[128], gh[64], sred[2];
  int mol = blockIdx.x, e = threadIdx.x;
  {
    float cs = 0;
    for (int c = 0; c < 4; c++) {
      int g = mol * 4 + c;
      float s = 0;
      for (int i = 0; i < 32; i++) s += hb[((size_t)(g * 32 + i)) * 128 + e];
      cs += s * (1.0f / 32.0f);
    }
    cs *= 0.25f;
    float s2 = 0;
    int g = 64 + mol;
    for (int i = 0; i < 32; i++) s2 += hb[((size_t)(g * 32 + i)) * 128 + e];
    T[e] = cs + s2 * (1.0f / 32.0f);
    float ss = 0;
    for (int l = 0; l < 128; l++) ss += xs[((size_t)(mol * 128 + l)) * 128 + e];
    S[e] = ss * (1.0f / 128.0f);
  }
  __syncthreads();
  if (e < 64) {
    float a = fg1b[e];
    for (int f = 0; f < 128; f++) a += T[f] * fg1w[f * 64 + e];
    for (int f = 0; f < 128; f++) a += S[f] * fg1w[(128 + f) * 64 + e];
    gh[e] = fmaxf(a, 0.0f);
  }
  __syncthreads();
  {
    float a = fg2b[e];
    for (int j = 0; j < 64; j++) a += gh[j] * fg2w[j * 128 + e];
    float gate = 1.0f / (1.0f + expf(-a));
    float fu = gate * T[e] + (1.0f - gate) * S[e];
    G[e] = fu; Sm[e] = fu;
  }
  __syncthreads();
  for (int l = 0; l < 2; l++) {
    const float* vw = g2s_vw + (size_t)l * 16384; const float* vb = g2s_vb + l * 128;
    const float* ow = g2s_ow + (size_t)l * 16384; const float* ob = g2s_ob + l * 128;
    float a = vb[e];
    for (int f = 0; f < 128; f++) a += Sm[f] * vw[f * 128 + e];
    t1[e] = a;
    __syncthreads();
    a = ob[e];
    for (int f = 0; f < 128; f++) a += t1[f] * ow[f * 128 + e];
    float nv = blk_norm(G[e] + a, e, sred);
    G[e] = nv * n1g[l * 128 + e] + n1b[l * 128 + e];
    __syncthreads();
    const float* vw2 = s2g_vw + (size_t)l * 16384; const float* vb2 = s2g_vb + l * 128;
    const float* ow2 = s2g_ow + (size_t)l * 16384; const float* ob2 = s2g_ob + l * 128;
    a = vb2[e];
    for (int f = 0; f < 128; f++) a += G[f] * vw2[f * 128 + e];
    t1[e] = a;
    __syncthreads();
    a = ob2[e];
    for (int f = 0; f < 128; f++) a += t1[f] * ow2[f * 128 + e];
    nv = blk_norm(Sm[e] + a, e, sred);
    Sm[e] = nv * n2g[l * 128 + e] + n2b[l * 128 + e];
    __syncthreads();
  }
  t2[e] = 0.5f * (G[e] + Sm[e]);
  __syncthreads();
  float a = r1b[e];
  for (int f = 0; f < 128; f++) a += t2[f] * r1w[f * 128 + e];
  for (int f = 0; f < 3; f++) a += gfeat[mol * 3 + f] * r1w[(128 + f) * 128 + e];
  a = fmaxf(a, 0.0f);
  float p = a * r2w[e];
  #pragma unroll
  for (int o = 1; o < 64; o <<= 1) p += __shfl_xor(p, o);
  if ((e & 63) == 0) sred[e >> 6] = p;
  __syncthreads();
  if (e == 0) out[mol] = sred[0] + sred[1] + r2b[0];
}

// ================================================================ host
extern "C" void kernel_launch(void* const* d_in, const int* in_sizes, int n_in,
                              void* d_out, int out_size, void* d_ws, size_t ws_size,
                              hipStream_t stream)
{
  (void)n_in; (void)out_size; (void)ws_size;
  const bool dict = (in_sizes[1] == 8192);
  auto IN = [&](int di, int si) { return d_in[dict ? di : si]; };

  const float* conf_x   = (const float*)IN(0, 0);
  const int*   conf_ei  = (const int*)  IN(1, 63);
  const float* conf_ea  = (const float*)IN(2, 1);
  const float* conf_pos = (const float*)IN(3, 2);
  const float* scaf_x   = (const float*)IN(4, 3);
  const int*   scaf_ei  = (const int*)  IN(5, 64);
  const float* scaf_ea  = (const float*)IN(6, 4);
  const float* scaf_pos = (const float*)IN(7, 5);
  const int*   tokens   = (const int*)  IN(8, 65);
  const float* gfeat    = (const float*)IN(9, 6);
  const float* gproj_w  = (const float*)IN(11, 7);
  const float* gproj_b  = (const float*)IN(12, 8);
  const float* elin_w   = (const float*)IN(13, 9);
  const float* elin_b   = (const float*)IN(14, 10);
  const float* eln_g    = (const float*)IN(15, 11);
  const float* eln_b    = (const float*)IN(16, 12);
  const float* gt_qw    = (const float*)IN(17, 13);
  const float* gt_qb    = (const float*)IN(18, 14);
  const float* gt_kw    = (const float*)IN(19, 15);
  const float* gt_kb    = (const float*)IN(20, 16);
  const float* gt_vw    = (const float*)IN(21, 17);
  const float* gt_vb    = (const float*)IN(22, 18);
  const float* gt_ow    = (const float*)IN(23, 19);
  const float* gt_ob    = (const float*)IN(24, 20);
  const float* gt_ln1g  = (const float*)IN(25, 21);
  const float* gt_ln1b  = (const float*)IN(26, 22);
  const float* gt_f1w   = (const float*)IN(27, 23);
  const float* gt_f1b   = (const float*)IN(28, 24);
  const float* gt_f2w   = (const float*)IN(29, 25);
  const float* gt_f2b   = (const float*)IN(30, 26);
  const float* gt_ln2g  = (const float*)IN(31, 27);
  const float* gt_ln2b  = (const float*)IN(32, 28);
  const float* tok_emb  = (const float*)IN(33, 29);
  const float* pos_emb  = (const float*)IN(34, 30);
  const float* se_inw   = (const float*)IN(35, 31);
  const float* se_inb   = (const float*)IN(36, 32);
  const float* se_ow    = (const float*)IN(37, 33);
  const float* se_ob    = (const float*)IN(38, 34);
  const float* se_ln1g  = (const float*)IN(39, 35);
  const float* se_ln1b  = (const float*)IN(40, 36);
  const float* se_f1w   = (const float*)IN(41, 37);
  const float* se_f1b   = (const float*)IN(42, 38);
  const float* se_f2w   = (const float*)IN(43, 39);
  const float* se_f2b   = (const float*)IN(44, 40);
  const float* se_ln2g  = (const float*)IN(45, 41);
  const float* se_ln2b  = (const float*)IN(46, 42);
  const float* fg1_w    = (const float*)IN(47, 43);
  const float* fg1_b    = (const float*)IN(48, 44);
  const float* fg2_w    = (const float*)IN(49, 45);
  const float* fg2_b    = (const float*)IN(50, 46);
  const float* cm_g2s_vw = (const float*)IN(51, 47);
  const float* cm_g2s_vb = (const float*)IN(52, 48);
  const float* cm_g2s_ow = (const float*)IN(53, 49);
  const float* cm_g2s_ob = (const float*)IN(54, 50);
  const float* cm_s2g_vw = (const float*)IN(55, 53);
  const float* cm_s2g_vb = (const float*)IN(56, 54);
  const float* cm_s2g_ow = (const float*)IN(57, 55);
  const float* cm_s2g_ob = (const float*)IN(58, 56);
  const float* cm_n1g   = (const float*)IN(59, 51);
  const float* cm_n1b   = (const float*)IN(60, 52);
  const float* cm_n2g   = (const float*)IN(61, 57);
  const float* cm_n2b   = (const float*)IN(62, 58);
  const float* r1_w     = (const float*)IN(63, 59);
  const float* r1_b     = (const float*)IN(64, 60);
  const float* r2_w     = (const float*)IN(65, 61);
  const float* r2_b     = (const float*)IN(66, 62);
  float* out = (float*)d_out;

  // ---- workspace (fp32): graph & seq regions DISJOINT (concurrent) ----
  float* w = (float*)d_ws;
  size_t off = 0;
  auto alloc = [&](size_t n) { float* p = w + off; off += n; return p; };
  float* h     = alloc(2560 * 128);
  float* aggr  = alloc(2560 * 128);
  float* hb    = alloc(2560 * 128);
  float* distb = alloc(80 * 1024);
  float* qb    = alloc(3 * 327680);     // graph q/k/v
  float* atto  = alloc(327680);
  float* xs2   = alloc(2048 * 128);
  float* qkv3  = alloc(2048 * 384);
  float* satto = alloc(2048 * 128);
  float* xsfin = alloc(2048 * 128);

  // ============ graph front-end ============
  node_proj_k<<<2560, 128, 0, stream>>>(conf_x, scaf_x, gproj_w, gproj_b, h, aggr);
  dist_k<<<80, 256, 0, stream>>>(conf_pos, scaf_pos, distb);
  edge_gemm_k<<<dim3(160, 7), 256, 0, stream>>>(conf_ea, scaf_ea, conf_ei, scaf_ei, h, elin_w, elin_b, aggr);
  ln_k<<<2560, 128, 0, stream>>>(aggr, h, eln_g, eln_b, hb);
  embed_k<<<2048, 128, 0, stream>>>(tokens, tok_emb, pos_emb, xs2);

  // ============ merged graph(3) + seq(4) transformer layers ============
  for (int l = 0; l < 4; l++) {
    const bool hasG = (l < 3);
    const int lg = hasG ? l : 0;
    const int gq = hasG ? 480 : 0;
    const int ga = hasG ? 640 : 0;
    const int gt = hasG ? 160 : 0;
    float* sOut = (l == 3) ? xsfin : xs2;
    qkv_k<<<gq + 384, 256, 0, stream>>>(gq,
        hb, gt_qw + (size_t)lg * 16384, gt_kw + (size_t)lg * 16384, gt_vw + (size_t)lg * 16384,
        gt_qb + lg * 128, gt_kb + lg * 128, gt_vb + lg * 128, qb,
        xs2, se_inw + (size_t)l * 49152, se_inb + l * 384, qkv3);
    attn_k<<<ga + 256, 256, 0, stream>>>(ga, qb, qb + 327680, qb + 655360, distb, atto, qkv3, satto);
    tail_k<<<gt + 128, 256, 0, stream>>>(gt,
        atto, gt_ow + (size_t)lg * 16384, gt_ob + lg * 128, hb,
        gt_ln1g + lg * 128, gt_ln1b + lg * 128,
        gt_f1w + (size_t)lg * 32768, gt_f1b + lg * 256,
        gt_f2w + (size_t)lg * 32768, gt_f2b + lg * 128,
        gt_ln2g + lg * 128, gt_ln2b + lg * 128, hb,
        satto, se_ow + (size_t)l * 16384, se_ob + l * 128, xs2,
        se_ln1g + l * 128, se_ln1b + l * 128,
        se_f1w + (size_t)l * 32768, se_f1b + l * 256,
        se_f2w + (size_t)l * 32768, se_f2b + l * 128,
        se_ln2g + l * 128, se_ln2b + l * 128, sOut);
  }

  // ============ pool + smean + fusion + cross-modal + regressor ============
  head_k<<<16, 128, 0, stream>>>(hb, xsfin, gfeat,
                                 fg1_w, fg1_b, fg2_w, fg2_b,
                                 cm_g2s_vw, cm_g2s_vb, cm_g2s_ow, cm_g2s_ob, cm_n1g, cm_n1b,
                                 cm_s2g_vw, cm_s2g_vb, cm_s2g_ow, cm_s2g_ob, cm_n2g, cm_n2b,
                                 r1_w, r1_b, r2_w, r2_b, out);
}